// Round 9
// baseline (242.188 us; speedup 1.0000x reference)
//
#include <hip/hip_runtime.h>
#include <stdint.h>

typedef unsigned short u16;
typedef short short8 __attribute__((ext_vector_type(8)));
typedef short short4v __attribute__((ext_vector_type(4)));
typedef float float4v __attribute__((ext_vector_type(4)));
typedef float float16v __attribute__((ext_vector_type(16)));
typedef uint32_t uint2v __attribute__((ext_vector_type(2)));

#define HW 4096
#define QSCL 0.18033688011112042f   /* 0.125 * log2(e), folded into Q at conv time */

// async global->LDS DMA: per-lane global addr, LDS dest = wave-uniform base + lane*16
#define GLOAD_LDS(g, l) __builtin_amdgcn_global_load_lds( \
    (const __attribute__((address_space(1))) void*)(g),   \
    (__attribute__((address_space(3))) void*)(l), 16, 0, 0)

static __device__ __forceinline__ u16 f2bf(float f) {
  union { float f; uint32_t u; } v; v.f = f;
  uint32_t r = v.u + 0x7fffu + ((v.u >> 16) & 1u);
  return (u16)(r >> 16);
}

// packed f32x2 -> bf16x2 (RNE), single instruction; src0 -> low half
static __device__ __forceinline__ uint32_t pkbf(float a, float b) {
  uint32_t r;
  asm("v_cvt_pk_bf16_f32 %0, %1, %2" : "=v"(r) : "v"(a), "v"(b));
  return r;
}
// v_permlane32_swap_b32: a.hi32lanes <-> b.lo32lanes (both regs modified)
static __device__ __forceinline__ void plswap(uint32_t &a, uint32_t &b) {
  asm("v_permlane32_swap_b32 %0, %1" : "+v"(a), "+v"(b));
}

union PU { uint32_t u[4]; short8 v; };

// ---- kernel 1: x [4,256,4096] f32 -> Xtp [4,66,66,256] bf16 (spatially padded; halo pre-zeroed)
__global__ __launch_bounds__(256) void k_xt(const float* __restrict__ x, u16* __restrict__ Xtp) {
  __shared__ float t[32][33];
  const int b = blockIdx.z, c0 = blockIdx.y * 32, p0 = blockIdx.x * 32;
  const int tid = threadIdx.x;
  const int l8 = tid >> 5, lp = tid & 31;
#pragma unroll
  for (int i = 0; i < 4; i++) {
    int c = l8 + i * 8;
    t[c][lp] = x[(size_t)(b * 256 + c0 + c) * HW + p0 + lp];
  }
  __syncthreads();
#pragma unroll
  for (int i = 0; i < 4; i++) {
    int p = l8 + i * 8;
    int pp = p0 + p;
    int y = pp >> 6, xx = pp & 63;
    Xtp[((size_t)(b * 66 + y + 1) * 66 + (xx + 1)) * 256 + c0 + lp] = f2bf(t[lp][p]);
  }
}

// ---- kernel 2: repack weights -> Wt [9][384][256] bf16 (ci contiguous), bcat[384] f32
__global__ __launch_bounds__(256) void k_wprep(const float* __restrict__ qw, const float* __restrict__ qb,
    const float* __restrict__ kw, const float* __restrict__ kb,
    const float* __restrict__ vw, const float* __restrict__ vb,
    u16* __restrict__ Wt, float* __restrict__ bcat) {
  int tid = blockIdx.x * 256 + threadIdx.x;
  if (tid < 9 * 384 * 256) {
    int ci = tid & 255;
    int n = (tid >> 8) % 384;
    int off = tid / (384 * 256);
    float val;
    if (n < 64)       val = qw[(size_t)n * 2304 + ci * 9 + off];
    else if (n < 128) val = kw[(size_t)(n - 64) * 2304 + ci * 9 + off];
    else              val = vw[(size_t)(n - 128) * 2304 + ci * 9 + off];
    Wt[tid] = f2bf(val);
  }
  if (tid < 384) bcat[tid] = (tid < 64) ? qb[tid] : (tid < 128) ? kb[tid - 64] : vb[tid - 128];
}

// ---- kernel 3: fused QKV conv (proven structure; Q outputs pre-scaled by QSCL).
__global__ __launch_bounds__(256) void k_conv(const u16* __restrict__ Xtp,
    const u16* __restrict__ Wt, const float* __restrict__ bcat,
    u16* __restrict__ Qt, u16* __restrict__ Kt, u16* __restrict__ Vcf) {
  __shared__ __align__(16) u16 Als[2][128 * 64];   // 16 KB per buf [row pos][64 k]
  __shared__ __align__(16) u16 Bls[2][64 * 64];    // 8 KB per buf  [row ch ][64 k]
  const int tid = threadIdx.x;
  const int b = blockIdx.z, ct = blockIdx.y;       // ct: 0=Q, 1=K, 2..5=V slices
  const int p0 = blockIdx.x * 128, n0 = ct * 64;
  const int w = tid >> 6, lane = tid & 63, l16 = lane & 15, quad = lane >> 4;

  const int lr = lane >> 3, lcx = (lane & 7) ^ lr;
  const u16* ag[4];
#pragma unroll
  for (int g = 0; g < 4; g++) {
    const int pos = p0 + w * 32 + g * 8 + lr;
    const int py = pos >> 6, px = pos & 63;
    ag[g] = Xtp + ((size_t)(b * 66 + py) * 66 + px) * 256 + lcx * 8;
  }
  const u16* bg[2];
#pragma unroll
  for (int g = 0; g < 2; g++)
    bg[g] = Wt + (size_t)(n0 + w * 16 + g * 8 + lr) * 256 + lcx * 8;

  const int rx = l16 & 7;

  float4v acc[2][4];
  const float4v zz = {0.f, 0.f, 0.f, 0.f};
#pragma unroll
  for (int i = 0; i < 2; i++)
#pragma unroll
    for (int j = 0; j < 4; j++) acc[i][j] = zz;

#pragma unroll
  for (int g = 0; g < 4; g++) GLOAD_LDS(ag[g], &Als[0][(w * 32 + g * 8) * 64]);
#pragma unroll
  for (int g = 0; g < 2; g++) GLOAD_LDS(bg[g], &Bls[0][(w * 16 + g * 8) * 64]);
  __syncthreads();

  for (int ks = 0; ks < 36; ks++) {
    const int buf = ks & 1;
    if (ks + 1 < 36) {
      const int ksn = ks + 1, tap = ksn >> 2, cg = (ksn & 3) * 64;
      const int dy = (tap * 11) >> 5, dx = tap - dy * 3;
      const int aoff = (dy * 66 + dx) * 256 + cg;
      const size_t boff = (size_t)tap * 98304 + cg;
#pragma unroll
      for (int g = 0; g < 4; g++) GLOAD_LDS(ag[g] + aoff, &Als[buf ^ 1][(w * 32 + g * 8) * 64]);
#pragma unroll
      for (int g = 0; g < 2; g++) GLOAD_LDS(bg[g] + boff, &Bls[buf ^ 1][(w * 16 + g * 8) * 64]);
    }

    short8 af[2][2], bfv[4][2];
#pragma unroll
    for (int mt = 0; mt < 2; mt++)
#pragma unroll
      for (int kk = 0; kk < 2; kk++)
        af[mt][kk] = *(const short8*)&Als[buf][(w * 32 + mt * 16 + l16) * 64 + (((kk * 4 + quad) ^ rx) * 8)];
#pragma unroll
    for (int nt = 0; nt < 4; nt++)
#pragma unroll
      for (int kk = 0; kk < 2; kk++)
        bfv[nt][kk] = *(const short8*)&Bls[buf][(nt * 16 + l16) * 64 + (((kk * 4 + quad) ^ rx) * 8)];

    if (ct < 2) {
#pragma unroll
      for (int mt = 0; mt < 2; mt++)
#pragma unroll
        for (int nt = 0; nt < 4; nt++)
#pragma unroll
          for (int kk = 0; kk < 2; kk++)
            acc[mt][nt] = __builtin_amdgcn_mfma_f32_16x16x32_bf16(bfv[nt][kk], af[mt][kk], acc[mt][nt], 0, 0, 0);
    } else {
#pragma unroll
      for (int mt = 0; mt < 2; mt++)
#pragma unroll
        for (int nt = 0; nt < 4; nt++)
#pragma unroll
          for (int kk = 0; kk < 2; kk++)
            acc[mt][nt] = __builtin_amdgcn_mfma_f32_16x16x32_bf16(af[mt][kk], bfv[nt][kk], acc[mt][nt], 0, 0, 0);
    }
    __syncthreads();
  }

  if (ct < 2) {
    u16* base = (ct == 0) ? Qt : Kt;
    const float qs = (ct == 0) ? QSCL : 1.0f;
#pragma unroll
    for (int mt = 0; mt < 2; mt++) {
      const int p = p0 + w * 32 + mt * 16 + l16;
#pragma unroll
      for (int nt = 0; nt < 4; nt++) {
        const int nb = nt * 16 + quad * 4;
        short4v o;
#pragma unroll
        for (int r = 0; r < 4; r++) o[r] = (short)f2bf((acc[mt][nt][r] + bcat[ct * 64 + nb + r]) * qs);
        *(short4v*)(base + (size_t)(b * HW + p) * 64 + nb) = o;
      }
    }
  } else {
#pragma unroll
    for (int mt = 0; mt < 2; mt++) {
      const int pb = p0 + w * 32 + mt * 16 + quad * 4;
#pragma unroll
      for (int nt = 0; nt < 4; nt++) {
        const int cl = nt * 16 + l16;
        const int gc = (ct - 2) * 64 + cl;
        const float bias = bcat[ct * 64 + cl];
        short4v o;
#pragma unroll
        for (int r = 0; r < 4; r++) o[r] = (short)f2bf(acc[mt][nt][r] + bias);
        *(short4v*)(Vcf + (size_t)(b * 256 + gc) * HW + pb) = o;
      }
    }
  }
}

// ---- kernel 4: flash attention, R9 = 16 staging waves/CU (the delivery-rate fix).
// Cross-round law: per-wave DMA delivery ~1.5-3 B/cyc REGARDLESS of queue depth;
// total scales with #waves-staging (R5: 16 waves -> 17 B/cyc; m97: 12 waves,
// 3 blocks -> 22; every 4-8-wave attn config pinned at 10.6-12.7). R8 proved
// line density is NOT the limiter (dense 64-j = same per-wave rate as 32-j).
// R9: j-split across blocks (jh from blockIdx, grid 512 = 2 blocks/CU), 8-wave
// 512-thr blocks -> 16 staging waves/CU; 32-j tiles, 64 iters; V+K dbuf in only
// 40 KB LDS; per wave-iter: 3 shallow DMAs (2 V + 1 K), 8 MFMA, 16 exp2,
// 8 ds_read_b128; ONE __syncthreads/iter (stage-early, full-compute cover;
// cross-block interleave fills the drain). Softmax = R6-verified in-register
// cvt_pk + permlane32_swap. jh partials are ADDITIVE (no-max exp2 softmax):
// O/L partials -> workspace, combined by k_reduce.
// Wave (qa = w&1, cs = w>>1): 32 q x 64 ch; of[2][16] = 64 VGPR; QK/exp
// duplicated across cs (cheap; VALU/MFMA are slack pipes here).
__global__ __launch_bounds__(512, 4) void k_attn(const u16* __restrict__ Qt,
    const u16* __restrict__ Kt, const u16* __restrict__ Vcf,
    float* __restrict__ Opart, float* __restrict__ Lpart) {
  __shared__ __align__(16) u16 Vls[2][8192];   // 32 KB [buf][c 256][j 32] swizzled
  __shared__ __align__(16) u16 Kls[2][2048];   //  8 KB [buf][j 32][d 64] swizzled

  const int tid = threadIdx.x, bid = blockIdx.x;
  const int b = bid & 3;                       // XCD k -> batch k&3 (L2 pin)
  const int jh = (bid >> 2) & 1, it = bid >> 3;
  const int w = tid >> 6, lane = tid & 63;
  const int l32 = lane & 31, half = lane >> 5;
  const int qa = w & 1, cs = w >> 1;

  // staging lane constants (pre-swizzled global source, linear LDS dest)
  const int vr = lane >> 2, vcx = (lane & 3) ^ (vr & 3);   // V: 16 rows x 4 chunks
  const int lr = lane >> 3, lcx = (lane & 7) ^ lr;         // K: 8 rows x 8 chunks
  const char* vsrc = (const char*)Vcf + ((size_t)(b * 256 + w * 32 + vr)) * 8192
                     + jh * 4096 + vcx * 16;
  const char* ksrc = (const char*)Kt + ((size_t)(b * HW + jh * 2048 + (w & 3) * 8 + lr)) * 128
                     + lcx * 16;

  // Q as B-operand: B[k=d: half*8+e (+16/ks)][n=i: l32] (pre-scaled by QSCL)
  short8 qf[4];
  {
    const u16* qp = Qt + ((size_t)(b * HW + it * 64 + qa * 32 + l32)) * 64 + half * 8;
#pragma unroll
    for (int ks = 0; ks < 4; ks++) qf[ks] = *(const short8*)(qp + ks * 16);
  }

  const int rxk = l32 & 7, rxv = l32 & 3;
  const int krow = l32 * 64;
  const int vrow0 = (cs * 64 + l32) * 32;      // ct=0 rows; ct=1 -> +1024

  float16v of0, of1;
#pragma unroll
  for (int r = 0; r < 16; r++) { of0[r] = 0.f; of1[r] = 0.f; }
  float lp = 0.f;

#define STAGE(T, BUF) {                                                           \
    GLOAD_LDS(vsrc + (size_t)(T) * 64, &Vls[BUF][(w * 32) * 32]);                 \
    GLOAD_LDS(vsrc + (size_t)(T) * 64 + 16 * 8192, &Vls[BUF][(w * 32 + 16) * 32]);\
    GLOAD_LDS(ksrc + (size_t)(T) * 4096, &Kls[BUF][(w & 3) * 512]);               \
  }

#define COMPUTE(BUF) {                                                            \
    float16v s;                                                                   \
    _Pragma("unroll") for (int r = 0; r < 16; r++) s[r] = 0.f;                    \
    _Pragma("unroll") for (int ks = 0; ks < 4; ks++) {                            \
      short8 kf = *(const short8*)&Kls[BUF][krow + (((ks * 2 + half) ^ rxk) * 8)];\
      s = __builtin_amdgcn_mfma_f32_32x32x16_bf16(kf, qf[ks], s, 0, 0, 0);        \
    }                                                                             \
    float p0 = exp2f(s[0]),  p1 = exp2f(s[1]),  p2 = exp2f(s[2]),  p3 = exp2f(s[3]);   \
    float p4 = exp2f(s[4]),  p5 = exp2f(s[5]),  p6 = exp2f(s[6]),  p7 = exp2f(s[7]);   \
    float p8 = exp2f(s[8]),  p9 = exp2f(s[9]),  pa = exp2f(s[10]), pb_ = exp2f(s[11]); \
    float pc = exp2f(s[12]), pd = exp2f(s[13]), pe = exp2f(s[14]), pf = exp2f(s[15]);  \
    lp += ((p0 + p1) + (p2 + p3)) + ((p4 + p5) + (p6 + p7))                       \
        + ((p8 + p9) + (pa + pb_)) + ((pc + pd) + (pe + pf));                     \
    uint32_t c0 = pkbf(p0, p1), c1 = pkbf(p2, p3), c2 = pkbf(p4, p5), c3 = pkbf(p6, p7);   \
    plswap(c0, c2); plswap(c1, c3);                                               \
    uint32_t d0 = pkbf(p8, p9), d1 = pkbf(pa, pb_), d2 = pkbf(pc, pd), d3 = pkbf(pe, pf);  \
    plswap(d0, d2); plswap(d1, d3);                                               \
    PU pA, pB;                                                                    \
    pA.u[0] = c0; pA.u[1] = c1; pA.u[2] = c2; pA.u[3] = c3;                       \
    pB.u[0] = d0; pB.u[1] = d1; pB.u[2] = d2; pB.u[3] = d3;                       \
    const int ca = ((half ^ rxv) * 8), cb = (((2 + half) ^ rxv) * 8);             \
    short8 va0 = *(const short8*)&Vls[BUF][vrow0 + ca];                           \
    of0 = __builtin_amdgcn_mfma_f32_32x32x16_bf16(va0, pA.v, of0, 0, 0, 0);       \
    short8 vb0 = *(const short8*)&Vls[BUF][vrow0 + cb];                           \
    of0 = __builtin_amdgcn_mfma_f32_32x32x16_bf16(vb0, pB.v, of0, 0, 0, 0);       \
    short8 va1 = *(const short8*)&Vls[BUF][vrow0 + 1024 + ca];                    \
    of1 = __builtin_amdgcn_mfma_f32_32x32x16_bf16(va1, pA.v, of1, 0, 0, 0);       \
    short8 vb1 = *(const short8*)&Vls[BUF][vrow0 + 1024 + cb];                    \
    of1 = __builtin_amdgcn_mfma_f32_32x32x16_bf16(vb1, pB.v, of1, 0, 0, 0);       \
  }

  // ---- prologue: stage tile 0, drain
  STAGE(0, 0);
  __syncthreads();

  for (int t = 0; t < 64; t++) {
    const int buf = t & 1;
    if (t < 63) STAGE(t + 1, buf ^ 1);   // issued early; drained by the barrier below
    COMPUTE(buf);
    __syncthreads();                     // next tile landed; this buf free for t+2
  }
#undef COMPUTE
#undef STAGE

  // ---- epilogue: partial O / L straight to workspace (combined by k_reduce)
  lp += __shfl_xor(lp, 32);
  float* Ob = Opart + ((size_t)(jh * 4 + b) * 256) * 4096 + it * 64 + qa * 32 + l32;
#pragma unroll
  for (int ct = 0; ct < 2; ct++) {
    const float16v o = ct ? of1 : of0;
#pragma unroll
    for (int r = 0; r < 16; r++) {
      const int c = cs * 64 + ct * 32 + (r & 3) + 8 * (r >> 2) + 4 * half;
      Ob[(size_t)c * 4096] = o[r];
    }
  }
  if (cs == 0 && lane < 32)
    Lpart[(size_t)(jh * 4 + b) * 4096 + it * 64 + qa * 32 + l32] = lp;
}

// ---- kernel 5: combine jh partials: out = (O0 + O1) / (L0 + L1)
__global__ __launch_bounds__(256) void k_reduce(const float* __restrict__ Op,
    const float* __restrict__ Lp, float* __restrict__ out) {
  const int idx = blockIdx.x * 256 + threadIdx.x;    // one float4 each; 1048576 total
  const size_t f0 = (size_t)idx * 4;                 // f32 index = b*1048576 + c*4096 + i
  const int i = (int)(f0 & 4095);
  const int b = (int)(f0 >> 20);
  float4v o0 = *(const float4v*)(Op + f0);
  float4v o1 = *(const float4v*)(Op + f0 + 4194304);
  float4v l0 = *(const float4v*)(Lp + (size_t)b * 4096 + i);
  float4v l1 = *(const float4v*)(Lp + (size_t)(4 + b) * 4096 + i);
  float4v r;
#pragma unroll
  for (int k = 0; k < 4; k++) r[k] = (o0[k] + o1[k]) * (1.0f / (l0[k] + l1[k]));
  *(float4v*)(out + f0) = r;
}

extern "C" void kernel_launch(void* const* d_in, const int* in_sizes, int n_in,
                              void* d_out, int out_size, void* d_ws, size_t ws_size,
                              hipStream_t stream) {
  const float* x  = (const float*)d_in[0];
  const float* qw = (const float*)d_in[1];
  const float* qb = (const float*)d_in[2];
  const float* kw = (const float*)d_in[3];
  const float* kb = (const float*)d_in[4];
  const float* vw = (const float*)d_in[5];
  const float* vb = (const float*)d_in[6];
  float* out = (float*)d_out;
  char* ws = (char*)d_ws;
  u16*   Xtp = (u16*)(ws);
  u16*   Wt  = (u16*)(ws + 8921088);
  float* bc  = (float*)(ws + 10690560);
  u16*   Qt  = (u16*)(ws + 10692096);
  u16*   Kt  = (u16*)(ws + 12789248);
  u16*   Vcf = (u16*)(ws + 14886400);
  float* Op  = (float*)(ws + 23275008);   // [2 jh][4 b][256 c][4096 i] f32 = 33.5 MB
  float* Lp  = (float*)(ws + 56829440);   // [2 jh][4 b][4096 i] f32 = 128 KB

  hipMemsetAsync(Xtp, 0, 8921088, stream);  // zero the spatial halo
  k_xt  <<<dim3(128, 8, 4), 256, 0, stream>>>(x, Xtp);
  k_wprep<<<3456, 256, 0, stream>>>(qw, qb, kw, kb, vw, vb, Wt, bc);
  k_conv<<<dim3(32, 6, 4), 256, 0, stream>>>(Xtp, Wt, bc, Qt, Kt, Vcf);
  k_attn<<<512, 512, 0, stream>>>(Qt, Kt, Vcf, Op, Lp);
  k_reduce<<<4096, 256, 0, stream>>>(Op, Lp, out);
}